// Round 2
// 14944.505 us; speedup vs baseline: 1.0565x; 1.0565x over previous
//
#include <hip/hip_runtime.h>
#include <math.h>

// SARABrainCore: 16-step spiking recurrent net, B=1024 T=16 D=1024 H=2048 O=1024.
// R3: inputs fp32, outputs fp32, internals fp64 (spike threshold is chaotic;
// fp64 tracks the fp64 ground truth; absmax 0.0039 vs fp32 JAX ref is spike
// flips caused by the *reference's* fp32 rounding and is tolerance-accepted).
// R4: GEMM core moved from fp64 VALU (30 TF, VALUBusy 42%, 1e8 LDS-conflict
// cycles) to v_mfma_f64_16x16x4_f64 (78.6 TF matrix pipe, was idle).
// R5 (this round): fixed the f64 MFMA C/D row mapping. HW-verified on this
// bench: C/D row = (lane>>4) + 4*reg, col = lane&15 (regs stride 4 rows).
// R4 used row = 4*(lane>>4)+reg, a within-16-row involution P away from
// truth -- readout passed (P applied twice cancels) while the raw rec/attr
// dumps failed P-permuted. Do NOT "fix" this back to the bf16-style mapping.
//   - tile 64x128, 4 waves (2x2), each wave 32x64 = 2x4 MFMA tiles of 16x16.
//   - LDS k-major: As[16][64], Bs[16][130] (pad -> staging writes and
//     fragment reads both conflict-free).
//   - software-pipelined staging: prefetch K-tile k+1 into regs before
//     computing tile k, so global latency hides under the MFMA stream.
// Fragment layouts (f64 16x16x4): A: row=lane&15, k=lane>>4;
// B: col=lane&15, k=lane>>4; C/D: col=lane&15, row=(lane>>4)+4*reg.

#define BB 1024
#define TT 16
#define DD 1024
#define HH 2048
#define OO 1024

typedef double d4 __attribute__((ext_vector_type(4)));

// ---- element readers ----
struct RdF {                               // fp32 input array
    const float* p; long ld;
    __device__ double operator()(int r, int c) const { return (double)p[(long)r*ld + c]; }
};
struct RdD {                               // fp64 internal array
    const double* p; long ld;
    __device__ double operator()(int r, int c) const { return p[(long)r*ld + c]; }
};
struct RdSum {                             // ctx + rec computed on the fly (exact)
    const double* a; const double* b; long ld;
    __device__ double operator()(int r, int c) const { long i=(long)r*ld+c; return a[i]+b[i]; }
};
struct RdSpk {                             // spike count -> mean (x0.0625 exact)
    const float* p; long ld;
    __device__ double operator()(int r, int c) const { return (double)p[(long)r*ld+c] * 0.0625; }
};

#define LDB_S 130   // Bs row stride in doubles (128 + 2 pad)

// ---- fp64 MFMA GEMM core: 64(M) x 128(N) tile, 256 thr, BK=16 ----
// acc[i][j]: wave (wm,wn) owns rows [wm*32, wm*32+32), cols [wn*64, wn*64+64);
// i = M-tile (2 x 16 rows), j = N-tile (4 x 16 cols).
template<typename AR, typename BR>
__device__ __forceinline__ void gemm_mfma(AR A, BR B, int row0, int col0, int K,
                                          double* __restrict__ As,
                                          double* __restrict__ Bs,
                                          d4 acc[2][4])
{
    const int tid  = threadIdx.x;
    const int lane = tid & 63;
    const int wid  = tid >> 6;
    const int wm   = wid >> 1;            // 0..1
    const int wn   = wid & 1;             // 0..1
    const int l15  = lane & 15;
    const int l4   = lane >> 4;           // 0..3 = k within MFMA
    // A staging: 64 rows x 16 k, 4 elems/thread (row-contiguous global reads)
    const int am = tid >> 2, ak = (tid & 3) << 2;
    // B staging: 16 k x 128 cols, 8 elems/thread (col-contiguous global reads)
    const int bk = tid >> 4, bn = (tid & 15) << 3;

    double ar[4], br[8];
    #pragma unroll
    for (int j = 0; j < 4; ++j) ar[j] = A(row0 + am, ak + j);
    #pragma unroll
    for (int j = 0; j < 8; ++j) br[j] = B(bk, col0 + bn + j);

    for (int k0 = 0; k0 < K; k0 += 16) {
        __syncthreads();                  // prev tile's compute done
        #pragma unroll
        for (int j = 0; j < 4; ++j) As[(ak + j)*64 + am] = ar[j];
        #pragma unroll
        for (int j = 0; j < 8; ++j) Bs[bk*LDB_S + bn + j] = br[j];
        __syncthreads();
        if (k0 + 16 < K) {                // prefetch next K-tile into regs
            #pragma unroll
            for (int j = 0; j < 4; ++j) ar[j] = A(row0 + am, k0 + 16 + ak + j);
            #pragma unroll
            for (int j = 0; j < 8; ++j) br[j] = B(k0 + 16 + bk, col0 + bn + j);
        }
        #pragma unroll
        for (int ks = 0; ks < 4; ++ks) {
            const int kk = ks*4 + l4;
            double a0 = As[kk*64 + wm*32 +      l15];
            double a1 = As[kk*64 + wm*32 + 16 + l15];
            double b0 = Bs[kk*LDB_S + wn*64 +      l15];
            double b1 = Bs[kk*LDB_S + wn*64 + 16 + l15];
            double b2 = Bs[kk*LDB_S + wn*64 + 32 + l15];
            double b3 = Bs[kk*LDB_S + wn*64 + 48 + l15];
            acc[0][0] = __builtin_amdgcn_mfma_f64_16x16x4f64(a0, b0, acc[0][0], 0, 0, 0);
            acc[0][1] = __builtin_amdgcn_mfma_f64_16x16x4f64(a0, b1, acc[0][1], 0, 0, 0);
            acc[0][2] = __builtin_amdgcn_mfma_f64_16x16x4f64(a0, b2, acc[0][2], 0, 0, 0);
            acc[0][3] = __builtin_amdgcn_mfma_f64_16x16x4f64(a0, b3, acc[0][3], 0, 0, 0);
            acc[1][0] = __builtin_amdgcn_mfma_f64_16x16x4f64(a1, b0, acc[1][0], 0, 0, 0);
            acc[1][1] = __builtin_amdgcn_mfma_f64_16x16x4f64(a1, b1, acc[1][1], 0, 0, 0);
            acc[1][2] = __builtin_amdgcn_mfma_f64_16x16x4f64(a1, b2, acc[1][2], 0, 0, 0);
            acc[1][3] = __builtin_amdgcn_mfma_f64_16x16x4f64(a1, b3, acc[1][3], 0, 0, 0);
        }
    }
}

// Output element (i,j,r): row = row0 + wm*32 + i*16 + l4 + 4*r,   (HW-verified)
//                         col = col0 + wn*64 + j*16 + l15.
#define GEMM_EPILOG_VARS                                   \
    const int lane = threadIdx.x & 63;                     \
    const int wid  = threadIdx.x >> 6;                     \
    const int wm   = wid >> 1, wn = wid & 1;               \
    const int l15  = lane & 15, l4 = lane >> 4;

// ---- Wpf = Wp @ Wfc ----
__global__ __launch_bounds__(256) void k_wpf(const float* __restrict__ Wp,
                                             const float* __restrict__ Wfc,
                                             double* __restrict__ Wpf)
{
    __shared__ double As[16*64], Bs[16*LDB_S];
    d4 acc[2][4] = {};
    int row0 = blockIdx.y*64, col0 = blockIdx.x*128;
    gemm_mfma(RdF{Wp, HH}, RdF{Wfc, HH}, row0, col0, HH, As, Bs, acc);
    GEMM_EPILOG_VARS
    #pragma unroll
    for (int i=0;i<2;i++)
      #pragma unroll
      for (int j=0;j<4;j++)
        #pragma unroll
        for (int r=0;r<4;r++) {
            int d = row0 + wm*32 + i*16 + l4 + 4*r;
            int h = col0 + wn*64 + j*16 + l15;
            Wpf[(long)d*HH + h] = acc[i][j][r];
        }
}

// ---- bpf[h] = bp @ Wfc + bfc ----
__global__ __launch_bounds__(256) void k_bpf(const float* __restrict__ bp,
                                             const float* __restrict__ Wfc,
                                             const float* __restrict__ bfc,
                                             double* __restrict__ bpf)
{
    int h = blockIdx.x*256 + threadIdx.x;
    double acc = 0.0;
    for (int k = 0; k < HH; ++k)
        acc = fma((double)bp[k], (double)Wfc[(long)k*HH + h], acc);
    bpf[h] = acc + (double)bfc[h];
}

// ---- update = tanh(x_t @ Wpf + bpf); rec = BETA*rec + (1-BETA)*update ----
__global__ __launch_bounds__(256) void k_update(const float* __restrict__ x, int t,
                                                const double* __restrict__ Wpf,
                                                const double* __restrict__ bpf,
                                                double* __restrict__ rec)
{
    __shared__ double As[16*64], Bs[16*LDB_S];
    d4 acc[2][4] = {};
    int row0 = blockIdx.y*64, col0 = blockIdx.x*128;
    const float* x_t = x + (long)t*DD;              // row b at x[b*T*D + t*D]
    gemm_mfma(RdF{x_t, (long)TT*DD}, RdD{Wpf, HH}, row0, col0, DD, As, Bs, acc);
    GEMM_EPILOG_VARS
    const double BETA = 0.9;
    const double OMB  = 1.0 - BETA;   // Python fp64 semantics
    #pragma unroll
    for (int i=0;i<2;i++)
      #pragma unroll
      for (int j=0;j<4;j++)
        #pragma unroll
        for (int r=0;r<4;r++) {
            int b = row0 + wm*32 + i*16 + l4 + 4*r;
            int h = col0 + wn*64 + j*16 + l15;
            double u = tanh(acc[i][j][r] + bpf[h]);
            long idx = (long)b*HH + h;
            rec[idx] = BETA*rec[idx] + OMB*u;
        }
}

// ---- LayerNorm(rec) -> ctx  (one block per row) ----
__global__ __launch_bounds__(256) void k_ln(const double* __restrict__ rec,
                                            const float* __restrict__ gamma,
                                            const float* __restrict__ beta,
                                            double* __restrict__ ctx)
{
    __shared__ double red[256];
    int b = blockIdx.x, tid = threadIdx.x;
    const double* r = rec + (long)b*HH;
    double s = 0.0;
    for (int h = tid; h < HH; h += 256) s += r[h];
    red[tid] = s; __syncthreads();
    for (int off = 128; off > 0; off >>= 1) {
        if (tid < off) red[tid] += red[tid+off];
        __syncthreads();
    }
    double mean = red[0] / HH;
    __syncthreads();
    double v = 0.0;
    for (int h = tid; h < HH; h += 256) { double d = r[h]-mean; v += d*d; }
    red[tid] = v; __syncthreads();
    for (int off = 128; off > 0; off >>= 1) {
        if (tid < off) red[tid] += red[tid+off];
        __syncthreads();
    }
    double sd = sqrt(red[0] / HH + 1e-5);
    for (int h = tid; h < HH; h += 256) {
        long idx = (long)b*HH + h;
        ctx[idx] = (r[h]-mean)/sd * (double)gamma[h] + (double)beta[h];
    }
}

// ---- g = sigmoid((ctx+rec) @ Wg + bg); gated = g*ctx + (1-g)*rec ----
__global__ __launch_bounds__(256) void k_gate(const double* __restrict__ ctx,
                                              const double* __restrict__ rec,
                                              const float* __restrict__ Wg,
                                              const float* __restrict__ bg,
                                              double* __restrict__ gated)
{
    __shared__ double As[16*64], Bs[16*LDB_S];
    d4 acc[2][4] = {};
    int row0 = blockIdx.y*64, col0 = blockIdx.x*128;
    gemm_mfma(RdSum{ctx, rec, HH}, RdF{Wg, HH}, row0, col0, HH, As, Bs, acc);
    GEMM_EPILOG_VARS
    #pragma unroll
    for (int i=0;i<2;i++)
      #pragma unroll
      for (int j=0;j<4;j++)
        #pragma unroll
        for (int r=0;r<4;r++) {
            int b = row0 + wm*32 + i*16 + l4 + 4*r;
            int h = col0 + wn*64 + j*16 + l15;
            long idx = (long)b*HH + h;
            double g = 1.0/(1.0 + exp(-(acc[i][j][r] + (double)bg[h])));
            gated[idx] = g*ctx[idx] + (1.0-g)*rec[idx];
        }
}

// ---- current = gated@Wenc + attr@Wrec + benc + brec; LIF + spike count ----
__global__ __launch_bounds__(256) void k_current(const double* __restrict__ gated,
                                                 const float* __restrict__ Wenc,
                                                 const double* __restrict__ attr_in,
                                                 const float* __restrict__ Wrec,
                                                 const float* __restrict__ benc,
                                                 const float* __restrict__ brec,
                                                 double* __restrict__ attr_out,
                                                 float* __restrict__ spkcnt)
{
    __shared__ double As[16*64], Bs[16*LDB_S];
    d4 acc[2][4] = {};
    int row0 = blockIdx.y*64, col0 = blockIdx.x*128;
    gemm_mfma(RdD{gated,   HH}, RdF{Wenc, HH}, row0, col0, HH, As, Bs, acc);
    gemm_mfma(RdD{attr_in, HH}, RdF{Wrec, HH}, row0, col0, HH, As, Bs, acc);
    GEMM_EPILOG_VARS
    const double TAU = 2.0, THR = 1.0;
    #pragma unroll
    for (int i=0;i<2;i++)
      #pragma unroll
      for (int j=0;j<4;j++)
        #pragma unroll
        for (int r=0;r<4;r++) {
            int b = row0 + wm*32 + i*16 + l4 + 4*r;
            int h = col0 + wn*64 + j*16 + l15;
            long idx = (long)b*HH + h;
            double cur = acc[i][j][r] + (double)benc[h] + (double)brec[h];
            double a   = attr_in[idx];
            double nv  = a + (cur - a)/TAU;
            double sp  = (nv > THR) ? 1.0 : 0.0;
            attr_out[idx] = nv - sp*THR;
            spkcnt[idx] += (float)sp;
        }
}

// ---- out = (spkcnt/16) @ Wro + bro -> fp32 ----
__global__ __launch_bounds__(256) void k_readout(const float* __restrict__ spkcnt,
                                                 const float* __restrict__ Wro,
                                                 const float* __restrict__ bro,
                                                 float* __restrict__ out)
{
    __shared__ double As[16*64], Bs[16*LDB_S];
    d4 acc[2][4] = {};
    int row0 = blockIdx.y*64, col0 = blockIdx.x*128;
    gemm_mfma(RdSpk{spkcnt, HH}, RdF{Wro, OO}, row0, col0, HH, As, Bs, acc);
    GEMM_EPILOG_VARS
    #pragma unroll
    for (int i=0;i<2;i++)
      #pragma unroll
      for (int j=0;j<4;j++)
        #pragma unroll
        for (int r=0;r<4;r++) {
            int b = row0 + wm*32 + i*16 + l4 + 4*r;
            int o = col0 + wn*64 + j*16 + l15;
            out[(long)b*OO + o] = (float)(acc[i][j][r] + (double)bro[o]);
        }
}

__global__ __launch_bounds__(256) void k_d2f(const double* __restrict__ src,
                                             float* __restrict__ dst)
{
    long i = (long)blockIdx.x*256 + threadIdx.x;
    dst[i] = (float)src[i];
}

extern "C" void kernel_launch(void* const* d_in, const int* in_sizes, int n_in,
                              void* d_out, int out_size, void* d_ws, size_t ws_size,
                              hipStream_t stream) {
    const float* x    = (const float*)d_in[0];
    const float* Wp   = (const float*)d_in[1];
    const float* bp   = (const float*)d_in[2];
    const float* Wfc  = (const float*)d_in[3];
    const float* bfc  = (const float*)d_in[4];
    const float* gamma= (const float*)d_in[5];
    const float* beta = (const float*)d_in[6];
    const float* Wg   = (const float*)d_in[7];
    const float* bg   = (const float*)d_in[8];
    const float* Wenc = (const float*)d_in[9];
    const float* benc = (const float*)d_in[10];
    const float* Wrec = (const float*)d_in[11];
    const float* brec = (const float*)d_in[12];
    const float* Wro  = (const float*)d_in[13];
    const float* bro  = (const float*)d_in[14];
    float* out = (float*)d_out;

    const long NBH = (long)BB*HH;     // 2M elems
    char* p = (char*)d_ws;
    double* Wpf   = (double*)p; p += (long)DD*HH*sizeof(double);   // 16.8 MB
    double* bpf   = (double*)p; p += HH*sizeof(double);
    double* rec   = (double*)p; p += NBH*sizeof(double);           // 16.8 MB
    double* attrA = (double*)p; p += NBH*sizeof(double);           // 16.8 MB
    double* attrB = (double*)p; p += NBH*sizeof(double);           // 16.8 MB
    double* ctx   = (double*)p; p += NBH*sizeof(double);           // 16.8 MB
    double* gated = (double*)p; p += NBH*sizeof(double);           // 16.8 MB
    float*  spkcnt= (float*)p;  p += NBH*sizeof(float);            // 8.4 MB
    // total ~101 MB

    hipMemsetAsync(rec,    0, NBH*sizeof(double), stream);
    hipMemsetAsync(attrA,  0, NBH*sizeof(double), stream);
    hipMemsetAsync(spkcnt, 0, NBH*sizeof(float),  stream);

    dim3 blk(256);
    dim3 g_wpf(HH/128, DD/64);   // 16 x 16 = 256 blocks (1/CU)
    k_wpf<<<g_wpf, blk, 0, stream>>>(Wp, Wfc, Wpf);
    k_bpf<<<HH/256, blk, 0, stream>>>(bp, Wfc, bfc, bpf);

    dim3 g_step(HH/128, BB/64);  // 16 x 16 = 256 blocks (1/CU)
    double* ain  = attrA;
    double* aout = attrB;
    for (int t = 0; t < TT; ++t) {
        k_update <<<g_step, blk, 0, stream>>>(x, t, Wpf, bpf, rec);
        k_ln     <<<BB,     blk, 0, stream>>>(rec, gamma, beta, ctx);
        k_gate   <<<g_step, blk, 0, stream>>>(ctx, rec, Wg, bg, gated);
        k_current<<<g_step, blk, 0, stream>>>(gated, Wenc, ain, Wrec, benc, brec, aout, spkcnt);
        double* tmp = ain; ain = aout; aout = tmp;
    }
    // final attractor state in `ain`

    dim3 g_ro(OO/128, BB/64);    // 8 x 16 = 128 blocks
    k_readout<<<g_ro, blk, 0, stream>>>(spkcnt, Wro, bro, out);
    k_d2f<<<NBH/256, blk, 0, stream>>>(rec, out + (long)BB*OO);
    k_d2f<<<NBH/256, blk, 0, stream>>>(ain, out + (long)BB*OO + NBH);
}

// Round 4
// 10948.891 us; speedup vs baseline: 1.4420x; 1.3649x over previous
//
#include <hip/hip_runtime.h>
#include <math.h>

// SARABrainCore: 16-step spiking recurrent net, B=1024 T=16 D=1024 H=2048 O=1024.
// R3: inputs fp32, outputs fp32, internals fp64 (spike threshold is chaotic;
// fp64 tracks the fp64 ground truth; absmax 0.0039 vs fp32 JAX ref is spike
// flips from the reference's fp32 rounding, tolerance-accepted). fp32 GEMM is
// NOT safe: a single spike flip changes final attr by 1.0 >> 0.032 threshold.
// R4: GEMM moved to v_mfma_f64_16x16x4_f64 (78.6 TF matrix pipe).
// R5: HW-verified f64 MFMA C/D layout: row=(lane>>4)+4*reg, col=lane&15
// (regs stride 4 rows). R4's row=4*(lane>>4)+reg was an involution P off:
// readout passed (P twice cancels), raw rec/attr dumps failed. Keep this.
// R6: R5 was MFMA-issue-bound at 40% with 1 block/CU (grid 256, Occupancy
// 11.8%): every barrier/LDS-latency stall idled the MFMA pipe.
//   - tile 64x64, 4 waves (2x2), each wave 32x32 = 2x2 MFMA tiles
//     -> grid 512 = 2 independent blocks/CU (m114 co-scheduling).
//   - BK=32, double-buffered LDS, ONE __syncthreads per K-tile; register
//     prefetch of tile t+1 issued before compute (global latency hides
//     under 2048 cy of MFMA per wave per tile).
// R7 (this round): identical resubmit of R6 — the R6 bench died to an infra
// container failure (no pytest/compile output), not a kernel fault.
// Fragment layouts (f64 16x16x4): A: row=lane&15, k=lane>>4;
// B: col=lane&15, k=lane>>4; C/D: col=lane&15, row=(lane>>4)+4*reg.

#define BB 1024
#define TT 16
#define DD 1024
#define HH 2048
#define OO 1024

typedef double d4 __attribute__((ext_vector_type(4)));

// ---- element readers ----
struct RdF {                               // fp32 input array
    const float* p; long ld;
    __device__ double operator()(int r, int c) const { return (double)p[(long)r*ld + c]; }
};
struct RdD {                               // fp64 internal array
    const double* p; long ld;
    __device__ double operator()(int r, int c) const { return p[(long)r*ld + c]; }
};
struct RdSum {                             // ctx + rec computed on the fly (exact)
    const double* a; const double* b; long ld;
    __device__ double operator()(int r, int c) const { long i=(long)r*ld+c; return a[i]+b[i]; }
};
struct RdSpk {                             // spike count -> mean (x0.0625 exact)
    const float* p; long ld;
    __device__ double operator()(int r, int c) const { return (double)p[(long)r*ld+c] * 0.0625; }
};

#define LDBS 66                  // Bs row stride in doubles (64 + 2 pad)
#define TILE_A (64*32)           // 2048 doubles
#define TILE_B (32*LDBS)         // 2112 doubles
#define LDS_DBL (2*(TILE_A + TILE_B))   // 8320 doubles = 66.56 KB

// ---- fp64 MFMA GEMM core: 64x64 tile, 256 thr (4 waves 2x2), BK=32,
// ---- double-buffered LDS, 1 barrier/tile, register prefetch. ----
template<typename AR, typename BR>
__device__ __forceinline__ void gemm_mfma(AR A, BR B, int row0, int col0, int K,
                                          double* __restrict__ S,
                                          d4 acc[2][2])
{
    const int tid  = threadIdx.x;
    const int lane = tid & 63;
    const int wid  = tid >> 6;
    const int wm   = wid >> 1;            // 0..1
    const int wn   = wid & 1;             // 0..1
    const int l15  = lane & 15;
    const int l4   = lane >> 4;           // 0..3 = k within MFMA
    // A staging: 64 rows x 32 k, 8 elems/thread (k-contiguous global reads)
    const int am = tid >> 2, ak = (tid & 3) << 3;
    // B staging: 32 k x 64 cols, 8 elems/thread (col-contiguous global reads)
    const int bk = tid >> 3, bn = (tid & 7) << 3;

    double* A0 = S;
    double* B0 = S + TILE_A;
    double* A1 = S + TILE_A + TILE_B;
    double* B1 = A1 + TILE_A;

    double ar[8], br[8];
    #pragma unroll
    for (int j = 0; j < 8; ++j) ar[j] = A(row0 + am, ak + j);
    #pragma unroll
    for (int j = 0; j < 8; ++j) br[j] = B(bk, col0 + bn + j);

    __syncthreads();                      // prior users of S are done
    #pragma unroll
    for (int j = 0; j < 8; ++j) A0[(ak + j)*64 + am] = ar[j];
    #pragma unroll
    for (int j = 0; j < 8; ++j) B0[bk*LDBS + bn + j] = br[j];
    __syncthreads();

    double *cA = A0, *cB = B0, *nA = A1, *nB = B1;
    const int nt = K >> 5;
    for (int t = 0; t < nt; ++t) {
        if (t + 1 < nt) {                 // issue next-tile global loads early
            #pragma unroll
            for (int j = 0; j < 8; ++j) ar[j] = A(row0 + am, (t+1)*32 + ak + j);
            #pragma unroll
            for (int j = 0; j < 8; ++j) br[j] = B((t+1)*32 + bk, col0 + bn + j);
        }
        #pragma unroll
        for (int ks = 0; ks < 8; ++ks) {
            const int kk = ks*4 + l4;
            double a0 = cA[kk*64 + wm*32 +      l15];
            double a1 = cA[kk*64 + wm*32 + 16 + l15];
            double b0 = cB[kk*LDBS + wn*32 +      l15];
            double b1 = cB[kk*LDBS + wn*32 + 16 + l15];
            acc[0][0] = __builtin_amdgcn_mfma_f64_16x16x4f64(a0, b0, acc[0][0], 0, 0, 0);
            acc[0][1] = __builtin_amdgcn_mfma_f64_16x16x4f64(a0, b1, acc[0][1], 0, 0, 0);
            acc[1][0] = __builtin_amdgcn_mfma_f64_16x16x4f64(a1, b0, acc[1][0], 0, 0, 0);
            acc[1][1] = __builtin_amdgcn_mfma_f64_16x16x4f64(a1, b1, acc[1][1], 0, 0, 0);
        }
        if (t + 1 < nt) {                 // write-late into the other buffer
            #pragma unroll
            for (int j = 0; j < 8; ++j) nA[(ak + j)*64 + am] = ar[j];
            #pragma unroll
            for (int j = 0; j < 8; ++j) nB[bk*LDBS + bn + j] = br[j];
            __syncthreads();              // single barrier per K-tile
            double* x;
            x = cA; cA = nA; nA = x;
            x = cB; cB = nB; nB = x;
        }
    }
}

// Output element (i,j,r): row = row0 + wm*32 + i*16 + l4 + 4*r,  (HW-verified)
//                         col = col0 + wn*32 + j*16 + l15.
#define GEMM_EPILOG_VARS                                   \
    const int lane = threadIdx.x & 63;                     \
    const int wid  = threadIdx.x >> 6;                     \
    const int wm   = wid >> 1, wn = wid & 1;               \
    const int l15  = lane & 15, l4 = lane >> 4;

// ---- Wpf = Wp @ Wfc ----
__global__ __launch_bounds__(256) void k_wpf(const float* __restrict__ Wp,
                                             const float* __restrict__ Wfc,
                                             double* __restrict__ Wpf)
{
    __shared__ double S[LDS_DBL];
    d4 acc[2][2] = {};
    int row0 = blockIdx.y*64, col0 = blockIdx.x*64;
    gemm_mfma(RdF{Wp, HH}, RdF{Wfc, HH}, row0, col0, HH, S, acc);
    GEMM_EPILOG_VARS
    #pragma unroll
    for (int i=0;i<2;i++)
      #pragma unroll
      for (int j=0;j<2;j++)
        #pragma unroll
        for (int r=0;r<4;r++) {
            int d = row0 + wm*32 + i*16 + l4 + 4*r;
            int h = col0 + wn*32 + j*16 + l15;
            Wpf[(long)d*HH + h] = acc[i][j][r];
        }
}

// ---- bpf[h] = bp @ Wfc + bfc ----
__global__ __launch_bounds__(256) void k_bpf(const float* __restrict__ bp,
                                             const float* __restrict__ Wfc,
                                             const float* __restrict__ bfc,
                                             double* __restrict__ bpf)
{
    int h = blockIdx.x*256 + threadIdx.x;
    double acc = 0.0;
    for (int k = 0; k < HH; ++k)
        acc = fma((double)bp[k], (double)Wfc[(long)k*HH + h], acc);
    bpf[h] = acc + (double)bfc[h];
}

// ---- update = tanh(x_t @ Wpf + bpf); rec = BETA*rec + (1-BETA)*update ----
__global__ __launch_bounds__(256) void k_update(const float* __restrict__ x, int t,
                                                const double* __restrict__ Wpf,
                                                const double* __restrict__ bpf,
                                                double* __restrict__ rec)
{
    __shared__ double S[LDS_DBL];
    d4 acc[2][2] = {};
    int row0 = blockIdx.y*64, col0 = blockIdx.x*64;
    const float* x_t = x + (long)t*DD;              // row b at x[b*T*D + t*D]
    gemm_mfma(RdF{x_t, (long)TT*DD}, RdD{Wpf, HH}, row0, col0, DD, S, acc);
    GEMM_EPILOG_VARS
    const double BETA = 0.9;
    const double OMB  = 1.0 - BETA;   // Python fp64 semantics
    #pragma unroll
    for (int i=0;i<2;i++)
      #pragma unroll
      for (int j=0;j<2;j++)
        #pragma unroll
        for (int r=0;r<4;r++) {
            int b = row0 + wm*32 + i*16 + l4 + 4*r;
            int h = col0 + wn*32 + j*16 + l15;
            double u = tanh(acc[i][j][r] + bpf[h]);
            long idx = (long)b*HH + h;
            rec[idx] = BETA*rec[idx] + OMB*u;
        }
}

// ---- LayerNorm(rec) -> ctx  (one block per row) ----
__global__ __launch_bounds__(256) void k_ln(const double* __restrict__ rec,
                                            const float* __restrict__ gamma,
                                            const float* __restrict__ beta,
                                            double* __restrict__ ctx)
{
    __shared__ double red[256];
    int b = blockIdx.x, tid = threadIdx.x;
    const double* r = rec + (long)b*HH;
    double s = 0.0;
    for (int h = tid; h < HH; h += 256) s += r[h];
    red[tid] = s; __syncthreads();
    for (int off = 128; off > 0; off >>= 1) {
        if (tid < off) red[tid] += red[tid+off];
        __syncthreads();
    }
    double mean = red[0] / HH;
    __syncthreads();
    double v = 0.0;
    for (int h = tid; h < HH; h += 256) { double d = r[h]-mean; v += d*d; }
    red[tid] = v; __syncthreads();
    for (int off = 128; off > 0; off >>= 1) {
        if (tid < off) red[tid] += red[tid+off];
        __syncthreads();
    }
    double sd = sqrt(red[0] / HH + 1e-5);
    for (int h = tid; h < HH; h += 256) {
        long idx = (long)b*HH + h;
        ctx[idx] = (r[h]-mean)/sd * (double)gamma[h] + (double)beta[h];
    }
}

// ---- g = sigmoid((ctx+rec) @ Wg + bg); gated = g*ctx + (1-g)*rec ----
__global__ __launch_bounds__(256) void k_gate(const double* __restrict__ ctx,
                                              const double* __restrict__ rec,
                                              const float* __restrict__ Wg,
                                              const float* __restrict__ bg,
                                              double* __restrict__ gated)
{
    __shared__ double S[LDS_DBL];
    d4 acc[2][2] = {};
    int row0 = blockIdx.y*64, col0 = blockIdx.x*64;
    gemm_mfma(RdSum{ctx, rec, HH}, RdF{Wg, HH}, row0, col0, HH, S, acc);
    GEMM_EPILOG_VARS
    #pragma unroll
    for (int i=0;i<2;i++)
      #pragma unroll
      for (int j=0;j<2;j++)
        #pragma unroll
        for (int r=0;r<4;r++) {
            int b = row0 + wm*32 + i*16 + l4 + 4*r;
            int h = col0 + wn*32 + j*16 + l15;
            long idx = (long)b*HH + h;
            double g = 1.0/(1.0 + exp(-(acc[i][j][r] + (double)bg[h])));
            gated[idx] = g*ctx[idx] + (1.0-g)*rec[idx];
        }
}

// ---- current = gated@Wenc + attr@Wrec + benc + brec; LIF + spike count ----
__global__ __launch_bounds__(256) void k_current(const double* __restrict__ gated,
                                                 const float* __restrict__ Wenc,
                                                 const double* __restrict__ attr_in,
                                                 const float* __restrict__ Wrec,
                                                 const float* __restrict__ benc,
                                                 const float* __restrict__ brec,
                                                 double* __restrict__ attr_out,
                                                 float* __restrict__ spkcnt)
{
    __shared__ double S[LDS_DBL];
    d4 acc[2][2] = {};
    int row0 = blockIdx.y*64, col0 = blockIdx.x*64;
    gemm_mfma(RdD{gated,   HH}, RdF{Wenc, HH}, row0, col0, HH, S, acc);
    gemm_mfma(RdD{attr_in, HH}, RdF{Wrec, HH}, row0, col0, HH, S, acc);
    GEMM_EPILOG_VARS
    const double TAU = 2.0, THR = 1.0;
    #pragma unroll
    for (int i=0;i<2;i++)
      #pragma unroll
      for (int j=0;j<2;j++)
        #pragma unroll
        for (int r=0;r<4;r++) {
            int b = row0 + wm*32 + i*16 + l4 + 4*r;
            int h = col0 + wn*32 + j*16 + l15;
            long idx = (long)b*HH + h;
            double cur = acc[i][j][r] + (double)benc[h] + (double)brec[h];
            double a   = attr_in[idx];
            double nv  = a + (cur - a)/TAU;
            double sp  = (nv > THR) ? 1.0 : 0.0;
            attr_out[idx] = nv - sp*THR;
            spkcnt[idx] += (float)sp;
        }
}

// ---- out = (spkcnt/16) @ Wro + bro -> fp32 ----
__global__ __launch_bounds__(256) void k_readout(const float* __restrict__ spkcnt,
                                                 const float* __restrict__ Wro,
                                                 const float* __restrict__ bro,
                                                 float* __restrict__ out)
{
    __shared__ double S[LDS_DBL];
    d4 acc[2][2] = {};
    int row0 = blockIdx.y*64, col0 = blockIdx.x*64;
    gemm_mfma(RdSpk{spkcnt, HH}, RdF{Wro, OO}, row0, col0, HH, S, acc);
    GEMM_EPILOG_VARS
    #pragma unroll
    for (int i=0;i<2;i++)
      #pragma unroll
      for (int j=0;j<2;j++)
        #pragma unroll
        for (int r=0;r<4;r++) {
            int b = row0 + wm*32 + i*16 + l4 + 4*r;
            int o = col0 + wn*32 + j*16 + l15;
            out[(long)b*OO + o] = (float)(acc[i][j][r] + (double)bro[o]);
        }
}

__global__ __launch_bounds__(256) void k_d2f(const double* __restrict__ src,
                                             float* __restrict__ dst)
{
    long i = (long)blockIdx.x*256 + threadIdx.x;
    dst[i] = (float)src[i];
}

extern "C" void kernel_launch(void* const* d_in, const int* in_sizes, int n_in,
                              void* d_out, int out_size, void* d_ws, size_t ws_size,
                              hipStream_t stream) {
    const float* x    = (const float*)d_in[0];
    const float* Wp   = (const float*)d_in[1];
    const float* bp   = (const float*)d_in[2];
    const float* Wfc  = (const float*)d_in[3];
    const float* bfc  = (const float*)d_in[4];
    const float* gamma= (const float*)d_in[5];
    const float* beta = (const float*)d_in[6];
    const float* Wg   = (const float*)d_in[7];
    const float* bg   = (const float*)d_in[8];
    const float* Wenc = (const float*)d_in[9];
    const float* benc = (const float*)d_in[10];
    const float* Wrec = (const float*)d_in[11];
    const float* brec = (const float*)d_in[12];
    const float* Wro  = (const float*)d_in[13];
    const float* bro  = (const float*)d_in[14];
    float* out = (float*)d_out;

    const long NBH = (long)BB*HH;     // 2M elems
    char* p = (char*)d_ws;
    double* Wpf   = (double*)p; p += (long)DD*HH*sizeof(double);   // 16.8 MB
    double* bpf   = (double*)p; p += HH*sizeof(double);
    double* rec   = (double*)p; p += NBH*sizeof(double);           // 16.8 MB
    double* attrA = (double*)p; p += NBH*sizeof(double);           // 16.8 MB
    double* attrB = (double*)p; p += NBH*sizeof(double);           // 16.8 MB
    double* ctx   = (double*)p; p += NBH*sizeof(double);           // 16.8 MB
    double* gated = (double*)p; p += NBH*sizeof(double);           // 16.8 MB
    float*  spkcnt= (float*)p;  p += NBH*sizeof(float);            // 8.4 MB
    // total ~101 MB

    hipMemsetAsync(rec,    0, NBH*sizeof(double), stream);
    hipMemsetAsync(attrA,  0, NBH*sizeof(double), stream);
    hipMemsetAsync(spkcnt, 0, NBH*sizeof(float),  stream);

    dim3 blk(256);
    dim3 g_wpf(HH/64, DD/64);    // 32 x 16 = 512 blocks (2/CU)
    k_wpf<<<g_wpf, blk, 0, stream>>>(Wp, Wfc, Wpf);
    k_bpf<<<HH/256, blk, 0, stream>>>(bp, Wfc, bfc, bpf);

    dim3 g_step(HH/64, BB/64);   // 32 x 16 = 512 blocks (2/CU)
    double* ain  = attrA;
    double* aout = attrB;
    for (int t = 0; t < TT; ++t) {
        k_update <<<g_step, blk, 0, stream>>>(x, t, Wpf, bpf, rec);
        k_ln     <<<BB,     blk, 0, stream>>>(rec, gamma, beta, ctx);
        k_gate   <<<g_step, blk, 0, stream>>>(ctx, rec, Wg, bg, gated);
        k_current<<<g_step, blk, 0, stream>>>(gated, Wenc, ain, Wrec, benc, brec, aout, spkcnt);
        double* tmp = ain; ain = aout; aout = tmp;
    }
    // final attractor state in `ain`

    dim3 g_ro(OO/64, BB/64);     // 16 x 16 = 256 blocks
    k_readout<<<g_ro, blk, 0, stream>>>(spkcnt, Wro, bro, out);
    k_d2f<<<NBH/256, blk, 0, stream>>>(rec, out + (long)BB*OO);
    k_d2f<<<NBH/256, blk, 0, stream>>>(ain, out + (long)BB*OO + NBH);
}